// Round 1
// baseline (296.047 us; speedup 1.0000x reference)
//
#include <hip/hip_runtime.h>
#include <cstdint>
#include <cstddef>

typedef float  v4f __attribute__((ext_vector_type(4)));
typedef short  v8s __attribute__((ext_vector_type(8)));
typedef int    v4i __attribute__((ext_vector_type(4)));

#define BB 8
#define NN 2048
#define DD 128
#define TI 16
#define NEGV (-9e15f)

__device__ __forceinline__ unsigned short f2bf(float x) {
  unsigned u = __float_as_uint(x);
  u = u + 0x7FFFu + ((u >> 16) & 1u);   // round-to-nearest-even
  return (unsigned short)(u >> 16);
}

// ---------------------------------------------------------------------------
// K1 (MFMA): Wh = h @ W, Wh1 = Wh·a[:128], Wh2 = Wh·a[128:], whbT = bf16(Wh)^T.
// Unchanged from the 285µs version.
// ---------------------------------------------------------------------------
__global__ __launch_bounds__(256) void gat_k1(
    const float* __restrict__ h, const float* __restrict__ W, const float* __restrict__ a,
    short* __restrict__ whbT, float* __restrict__ wh1g, float* __restrict__ wh2g)
{
  __shared__ __align__(16) unsigned short wT[DD * 136];
  __shared__ __align__(16) unsigned short staging[DD * 72];

  const int tid  = threadIdx.x;
  const int lane = tid & 63;
  const int wid  = tid >> 6;
  const int m16  = lane & 15;
  const int quad = lane >> 4;
  const int b    = blockIdx.y;
  const int i0   = blockIdx.x * 64;

  {
    const v4f* W4 = (const v4f*)W;
    #pragma unroll
    for (int it = 0; it < 16; it++) {
      int idx = it * 256 + tid;
      int k  = idx >> 5;
      int c4 = (idx & 31) * 4;
      v4f wv = W4[idx];
      #pragma unroll
      for (int q = 0; q < 4; q++)
        wT[(c4 + q) * 136 + k] = f2bf(wv[q]);
    }
  }

  const float* hrow = h + (size_t)(b * NN + i0 + wid * 16 + m16) * DD;
  v8s af[4];
  #pragma unroll
  for (int ks = 0; ks < 4; ks++) {
    v4f x0 = *(const v4f*)(hrow + ks * 32 + quad * 8);
    v4f x1 = *(const v4f*)(hrow + ks * 32 + quad * 8 + 4);
    v8s t;
    t[0] = (short)f2bf(x0.x); t[1] = (short)f2bf(x0.y);
    t[2] = (short)f2bf(x0.z); t[3] = (short)f2bf(x0.w);
    t[4] = (short)f2bf(x1.x); t[5] = (short)f2bf(x1.y);
    t[6] = (short)f2bf(x1.z); t[7] = (short)f2bf(x1.w);
    af[ks] = t;
  }
  __syncthreads();

  v4f acc[8];
  #pragma unroll
  for (int t = 0; t < 8; t++) acc[t] = (v4f){0.f, 0.f, 0.f, 0.f};

  #pragma unroll
  for (int ks = 0; ks < 4; ks++) {
    #pragma unroll
    for (int t = 0; t < 8; t++) {
      v8s bf = *(const v8s*)&wT[(t * 16 + m16) * 136 + ks * 32 + quad * 8];
      acc[t] = __builtin_amdgcn_mfma_f32_16x16x32_bf16(af[ks], bf, acc[t], 0, 0, 0);
    }
  }

  {
    float a1v[8], a2v[8];
    #pragma unroll
    for (int t = 0; t < 8; t++) {
      a1v[t] = a[t * 16 + m16];
      a2v[t] = a[DD + t * 16 + m16];
    }
    #pragma unroll
    for (int r = 0; r < 4; r++) {
      float p1 = 0.f, p2 = 0.f;
      #pragma unroll
      for (int t = 0; t < 8; t++) {
        p1 += acc[t][r] * a1v[t];
        p2 += acc[t][r] * a2v[t];
      }
      #pragma unroll
      for (int off = 8; off > 0; off >>= 1) {
        p1 += __shfl_xor(p1, off);
        p2 += __shfl_xor(p2, off);
      }
      if (m16 == 0) {
        int gi = b * NN + i0 + wid * 16 + quad * 4 + r;
        wh1g[gi] = p1;
        wh2g[gi] = p2;
      }
    }
  }

  #pragma unroll
  for (int t = 0; t < 8; t++)
    #pragma unroll
    for (int r = 0; r < 4; r++)
      staging[(t * 16 + m16) * 72 + wid * 16 + quad * 4 + r] = f2bf(acc[t][r]);
  __syncthreads();

  #pragma unroll
  for (int it = 0; it < 4; it++) {
    int idx = it * 256 + tid;
    int c  = idx >> 3;
    int i8 = idx & 7;
    v8s val = *(const v8s*)&staging[c * 72 + i8 * 8];
    *(v8s*)(whbT + (size_t)b * DD * NN + (size_t)c * NN + i0 + i8 * 8) = val;
  }
}

// ---------------------------------------------------------------------------
// K0 (NEW): streaming adj pass. One wave per row (4 rows/block, 4096 blocks).
// Reads adj once at full BW, packs the >0 predicate into a 32-bit word per
// (row, lane-group) [same bit layout K2 already used: j = u*256 + w*4 + q,
// word w, bit u*4+q], and computes row max m and 1/sum on the fly.
// ---------------------------------------------------------------------------
__global__ __launch_bounds__(256) void gat_k0(
    const int* __restrict__ adj, const float* __restrict__ wh1g,
    const float* __restrict__ wh2g, unsigned* __restrict__ maskg,
    float* __restrict__ msg, float* __restrict__ rsg)
{
  const int tid  = threadIdx.x;
  const int lane = tid & 63;
  const int wid  = tid >> 6;
  const int b    = blockIdx.y;
  const int i    = blockIdx.x * 4 + wid;
  const size_t row = (size_t)b * NN + i;

  const v4i* arow = (const v4i*)(adj + row * NN);
  const v4f* w2   = (const v4f*)(wh2g + (size_t)b * NN);
  const float wh1v = wh1g[row];

  float e[32];
  float m = -INFINITY;
  unsigned mbits = 0u;
  #pragma unroll
  for (int u = 0; u < 8; u++) {
    v4i av  = __builtin_nontemporal_load(&arow[u * 64 + lane]);
    v4f w2v = w2[u * 64 + lane];
    #pragma unroll
    for (int q = 0; q < 4; q++) {
      bool mk = av[q] > 0;
      float x = wh1v + w2v[q];
      float ev = mk ? (x > 0.f ? x : 0.2f * x) : NEGV;
      e[u * 4 + q] = ev;
      m = fmaxf(m, ev);
      mbits |= (mk ? 1u : 0u) << (u * 4 + q);
    }
  }
  maskg[row * 64 + lane] = mbits;

  #pragma unroll
  for (int off = 32; off > 0; off >>= 1) m = fmaxf(m, __shfl_xor(m, off));
  float s = 0.f;
  #pragma unroll
  for (int k = 0; k < 32; k++) s += __expf(e[k] - m);
  #pragma unroll
  for (int off = 32; off > 0; off >>= 1) s += __shfl_xor(s, off);

  if (lane == 0) { msg[row] = m; rsg[row] = 1.f / s; }
}

// ---------------------------------------------------------------------------
// K2 (rewritten): barrier-free main loop. Each wave owns a j-quarter
// (512 j = 8 chunks of 64). Attention values are computed directly in MFMA
// A-fragment layout (lane = (row m16, k-offset quad*8)), so no LDS round-trip
// and no per-chunk __syncthreads. h' partials reduced across waves in LDS
// at the end (smem region reused — wh2s is dead by then).
// ---------------------------------------------------------------------------
__global__ __launch_bounds__(256, 4) void gat_k2(
    const float* __restrict__ h, const unsigned* __restrict__ maskg,
    const short* __restrict__ whbT, const float* __restrict__ wh1g,
    const float* __restrict__ wh2g, const float* __restrict__ msg,
    const float* __restrict__ rsg, float* __restrict__ out,
    float* __restrict__ attout)
{
  __shared__ __align__(16) float smem[4 * TI * DD];   // 32KB: wh2s (main) / redbuf (epilogue)
  __shared__ unsigned masks[TI * 68];                 // 4.25KB, padded (68%32=4 -> spread banks)
  __shared__ float wh1s[TI], ms_s[TI], rs_s[TI];

  const int tid  = threadIdx.x;
  const int lane = tid & 63;
  const int wid  = tid >> 6;
  const int m16  = lane & 15;
  const int quad = lane >> 4;
  const int b    = blockIdx.y;
  const int i0   = blockIdx.x * TI;

  float* wh2s = smem;
  {
    const v4f* w2g4 = (const v4f*)(wh2g + (size_t)b * NN);
    ((v4f*)wh2s)[tid]       = w2g4[tid];
    ((v4f*)wh2s)[tid + 256] = w2g4[tid + 256];
  }
  {
    const unsigned* mg = maskg + (size_t)(b * NN + i0) * 64;
    #pragma unroll
    for (int it = 0; it < 4; it++) {
      int idx = it * 256 + tid;
      masks[(idx >> 6) * 68 + (idx & 63)] = mg[idx];
    }
  }
  if (tid < TI) {
    wh1s[tid] = wh1g[b * NN + i0 + tid];
    ms_s[tid] = msg[b * NN + i0 + tid];
    rs_s[tid] = rsg[b * NN + i0 + tid];
  }
  __syncthreads();

  const float wh1v = wh1s[m16];
  const float mi   = ms_s[m16];
  const float rsi  = rs_s[m16];
  const short* whbT_b = whbT + (size_t)b * DD * NN;
  float* attrow = attout + (size_t)(b * NN + i0 + m16) * NN;

  v4f acc[8];
  #pragma unroll
  for (int t = 0; t < 8; t++) acc[t] = (v4f){0.f, 0.f, 0.f, 0.f};

  for (int c = 0; c < 8; c++) {
    const int j0   = wid * 512 + c * 64;
    const int ubit = (j0 >> 8) << 2;     // bit = (j>>8)*4 + (j&3); constant per chunk
    #pragma unroll
    for (int ks = 0; ks < 2; ks++) {
      const int jb = j0 + ks * 32 + quad * 8;
      v4f w2a = ((const v4f*)wh2s)[jb >> 2];          // broadcast reads (same addr per quad)
      v4f w2b = ((const v4f*)wh2s)[(jb >> 2) + 1];
      const int w0  = (jb >> 2) & 63;
      unsigned mwa = masks[m16 * 68 + w0];
      unsigned mwb = masks[m16 * 68 + w0 + 1];

      v4f at0, at1;
      v8s af;
      #pragma unroll
      for (int q = 0; q < 4; q++) {
        float x = wh1v + w2a[q];
        float ev = ((mwa >> (ubit + q)) & 1u) ? (x > 0.f ? x : 0.2f * x) : NEGV;
        float at = __expf(ev - mi) * rsi;
        at0[q] = at;
        af[q]  = (short)f2bf(at);
      }
      #pragma unroll
      for (int q = 0; q < 4; q++) {
        float x = wh1v + w2b[q];
        float ev = ((mwb >> (ubit + q)) & 1u) ? (x > 0.f ? x : 0.2f * x) : NEGV;
        float at = __expf(ev - mi) * rsi;
        at1[q] = at;
        af[4 + q] = (short)f2bf(at);
      }
      // contiguous 32B per lane; per row the 4 quads tile 128B
      __builtin_nontemporal_store(at0, (v4f*)(attrow + jb));
      __builtin_nontemporal_store(at1, (v4f*)(attrow + jb + 4));

      #pragma unroll
      for (int t = 0; t < 8; t++) {
        v8s bf = *(const v8s*)(whbT_b + (size_t)(t * 16 + m16) * NN + jb);
        acc[t] = __builtin_amdgcn_mfma_f32_16x16x32_bf16(af, bf, acc[t], 0, 0, 0);
      }
    }
  }

  // ---- cross-wave reduction of h' partials (each wave covered 512 j's)
  __syncthreads();                       // wh2s dead; reuse smem
  float* red = smem;
  #pragma unroll
  for (int t = 0; t < 8; t++)
    #pragma unroll
    for (int r = 0; r < 4; r++)
      red[wid * (TI * DD) + (quad * 4 + r) * DD + t * 16 + m16] = acc[t][r];
  __syncthreads();

  {
    const size_t base = (size_t)(b * NN + i0) * DD;
    #pragma unroll
    for (int it = 0; it < 2; it++) {
      int idx = it * 256 + tid;          // v4f index over the 16x128 tile
      v4f s0 = ((const v4f*)red)[idx];
      v4f s1 = ((const v4f*)red)[idx + 512];
      v4f s2 = ((const v4f*)red)[idx + 1024];
      v4f s3 = ((const v4f*)red)[idx + 1536];
      v4f hv = *(const v4f*)(h + base + (size_t)idx * 4);
      v4f o  = hv + s0 + s1 + s2 + s3;
      *(v4f*)(out + base + (size_t)idx * 4) = o;
    }
  }
}

extern "C" void kernel_launch(void* const* d_in, const int* in_sizes, int n_in,
                              void* d_out, int out_size, void* d_ws, size_t ws_size,
                              hipStream_t stream) {
  const float* h  = (const float*)d_in[0];
  const int* adj  = (const int*)d_in[1];
  const float* W  = (const float*)d_in[2];
  const float* a  = (const float*)d_in[3];

  float* out    = (float*)d_out;
  float* attout = out + (size_t)BB * NN * DD;

  char* ws = (char*)d_ws;
  short* whbT = (short*)ws;                      ws += (size_t)BB * DD * NN * 2;  // 8.39MB
  float* wh1  = (float*)ws;                      ws += (size_t)BB * NN * 4;
  float* wh2  = (float*)ws;                      ws += (size_t)BB * NN * 4;
  float* msg  = (float*)ws;                      ws += (size_t)BB * NN * 4;
  float* rsg  = (float*)ws;                      ws += (size_t)BB * NN * 4;
  unsigned* maskg = (unsigned*)ws;               // 4MB

  gat_k1<<<dim3(NN / 64, BB), 256, 0, stream>>>(h, W, a, whbT, wh1, wh2);
  gat_k0<<<dim3(NN / 4, BB), 256, 0, stream>>>(adj, wh1, wh2, maskg, msg, rsg);
  gat_k2<<<dim3(NN / TI, BB), 256, 0, stream>>>(h, maskg, whbT, wh1, wh2, msg, rsg, out, attout);
}